// Round 5
// baseline (803.174 us; speedup 1.0000x reference)
//
#include <hip/hip_runtime.h>
#include <cstddef>
#include <cstdint>

#define NB 4
#define NP 8192
#define NK 16
#define NC 128
#define RELW 40    // rel K-extension row stride (elems): 20 dw, conflict-free
#define UINW 264   // UIN row stride: 132 dw % 32 = 4 -> benign

using short8   = __attribute__((ext_vector_type(8))) short;
using ushort4v = __attribute__((ext_vector_type(4))) unsigned short;
using floatx4  = __attribute__((ext_vector_type(4))) float;

__device__ __forceinline__ unsigned short f2bf(float f) {
    union { float f; unsigned u; } v; v.f = f;
    unsigned r = v.u + 0x7FFFu + ((v.u >> 16) & 1u);   // RNE
    return (unsigned short)(r >> 16);
}

// XOR-swizzled (rows x 128) bf16 tile, phys elem index. 8-col groups stay
// contiguous (b128-friendly); col-group ^= (row&15) spreads banks uniformly.
__device__ __forceinline__ int hsw(int row, int col) {
    return (row << 7) + ((((col >> 3) ^ (row & 15))) << 3) + (col & 7);
}

#define MFMA(a, b, c) __builtin_amdgcn_mfma_f32_16x16x32_bf16((a), (b), (c), 0, 0, 0)

// ---------------------------------------------------------------------------
// prep: Fbf0 = bf16(features)  +  weight packing (eW1 reordered to
// [feat(128)|rel(3)|pad->160], all others straight fp32->bf16).
// ---------------------------------------------------------------------------
__global__ void prep_k(const float* __restrict__ feat,
                       const float* __restrict__ offW1,
                       const float* __restrict__ eW1,
                       const float* __restrict__ eW2,
                       const float* __restrict__ uW1,
                       const float* __restrict__ uW2,
                       unsigned short* __restrict__ Fbf0,
                       unsigned short* __restrict__ offW1p,
                       unsigned short* __restrict__ eW1p,
                       unsigned short* __restrict__ eW2p,
                       unsigned short* __restrict__ uW1p,
                       unsigned short* __restrict__ uW2p)
{
    int blk = blockIdx.x;
    if (blk < 2048) {
        int i = (blk * 256 + threadIdx.x) * 8;
        float4 f0 = *(const float4*)(feat + i);
        float4 f1 = *(const float4*)(feat + i + 4);
        short8 u;
        u[0] = f2bf(f0.x); u[1] = f2bf(f0.y); u[2] = f2bf(f0.z); u[3] = f2bf(f0.w);
        u[4] = f2bf(f1.x); u[5] = f2bf(f1.y); u[6] = f2bf(f1.z); u[7] = f2bf(f1.w);
        *(short8*)(Fbf0 + i) = u;
        return;
    }
    int i = (blk - 2048) * 256 + threadIdx.x;
    if (i < 16384) { offW1p[i] = f2bf(offW1[i]); return; }
    i -= 16384;
    if (i < 61440) {
        int tt = i / 20480, rem = i % 20480;
        int j = rem / 160, k = rem % 160;
        float v = 0.f;
        if (k < 128)      v = eW1[(tt * 128 + j) * 131 + 3 + k];     // feat part
        else if (k < 131) v = eW1[(tt * 128 + j) * 131 + (k - 128)]; // rel part
        eW1p[i] = f2bf(v);
        return;
    }
    i -= 61440;
    if (i < 49152) { eW2p[i] = f2bf(eW2[i]); return; }
    i -= 49152;
    if (i < 98304) { uW1p[i] = f2bf(uW1[i]); return; }
    i -= 98304;
    if (i < 49152) { uW2p[i] = f2bf(uW2[i]); }
}

// ---------------------------------------------------------------------------
// Fused iteration. Block = 256 thr (4 waves), 8 points, edge rows in 2 halves
// of 64. LDS ~29.8 KB -> 4 blocks/CU.
// Register-pressure discipline (round-3/4 scratch lesson): NO long-lived
// weight fragments overlapping other stages — edge L1 weights are reloaded
// per half (L2-hot), offset temps are scoped.
// ---------------------------------------------------------------------------
__global__ __launch_bounds__(256, 4)
void stab_iter_k(const float* __restrict__ Fin, float* __restrict__ Fout,
                 const unsigned short* __restrict__ Fbf,
                 unsigned short* __restrict__ FbfN,
                 const float* __restrict__ xyz, const int* __restrict__ knn,
                 const unsigned short* __restrict__ offW1p,
                 const float* __restrict__ offW2,
                 const float* __restrict__ offb1,
                 const float* __restrict__ offb2,
                 const unsigned short* __restrict__ eW1p,
                 const unsigned short* __restrict__ eW2p,
                 const float* __restrict__ eb1, const float* __restrict__ eb2,
                 const unsigned short* __restrict__ uW1p,
                 const unsigned short* __restrict__ uW2p,
                 const float* __restrict__ ub1, const float* __restrict__ ub2)
{
    __shared__ __align__(16) unsigned short s_EIF[64 * NC];    // 16384 B: feats / H / UIN
    __shared__ __align__(16) unsigned short s_REL[64 * RELW];  //  5120 B: rel / HOFF / H2
    __shared__ __align__(16) float s_AGG[8 * NC];              //  4096 B: agg (OFFA alias)
    __shared__ __align__(16) float s_FSELF[8 * NC];            //  4096 B
    __shared__ int   s_KNN[128];                               //   512 B
    __shared__ float s_CTR[8][3];                              //    96 B

    const int xcd  = blockIdx.x & 7;
    const int slot = blockIdx.x >> 3;
    const int b    = xcd >> 1;
    const int n0   = ((slot << 1) | (xcd & 1)) << 3;
    const int t = threadIdx.x, wv = t >> 6, ln = t & 63;
    const int q = ln >> 4, r = ln & 15, cg0 = wv << 1;
    const size_t rowbase = (size_t)b * NP + n0;

    // ---------------- stage 0: self feats + knn ----------------
    unsigned short* OFFA = (unsigned short*)s_AGG;   // 16x128 swizzled bf16
    {
        int row = t >> 5, c4 = (t & 31) << 2;
        float4 f = *(const float4*)(Fin + (rowbase + row) * NC + c4);
        *(float4*)&s_FSELF[row * NC + c4] = f;
        ushort4v u = { f2bf(f.x), f2bf(f.y), f2bf(f.z), f2bf(f.w) };
        *(ushort4v*)&OFFA[hsw(row, c4)] = u;
        ushort4v z = {0, 0, 0, 0};
        *(ushort4v*)&OFFA[hsw(row + 8, c4)] = z;     // zero rows 8..15
        if (t < 128)
            s_KNN[t] = knn[(rowbase + (t >> 4)) * NK + (t & 15)];
    }
    float eb1v[2] = { eb1[cg0 * 16 + r], eb1[(cg0 + 1) * 16 + r] };
    float eb2v[2] = { eb2[cg0 * 16 + r], eb2[(cg0 + 1) * 16 + r] };
    __syncthreads();   // B1: OFFA/FSELF/KNN ready

    // ---------------- offset MLP layer 1 -> HOFF (s_REL, swizzled) ----------
    unsigned short* HOFF = s_REL;
    {
        short8 wf[2][4];
#pragma unroll
        for (int c = 0; c < 2; ++c)
#pragma unroll
            for (int ks = 0; ks < 4; ++ks)
                wf[c][ks] = *(const short8*)(offW1p + ((cg0 + c) * 16 + r) * NC + ks * 32 + q * 8);
        short8 af[4];
#pragma unroll
        for (int ks = 0; ks < 4; ++ks)
            af[ks] = *(const short8*)&OFFA[hsw(r, ks * 32 + q * 8)];
        floatx4 acc[2] = { {0.f,0.f,0.f,0.f}, {0.f,0.f,0.f,0.f} };
#pragma unroll
        for (int c = 0; c < 2; ++c)
#pragma unroll
            for (int ks = 0; ks < 4; ++ks)
                acc[c] = MFMA(af[ks], wf[c][ks], acc[c]);
#pragma unroll
        for (int c = 0; c < 2; ++c) {
            int col = (cg0 + c) * 16 + r;
            float bv = offb1[col];
#pragma unroll
            for (int i = 0; i < 4; ++i)
                HOFF[hsw(q * 4 + i, col)] = f2bf(fmaxf(acc[c][i] + bv, 0.f));
        }
    }
    __syncthreads();   // B2: HOFF ready

    // ---------------- offset MLP layer 2 (wave 0) -> centers ----------------
    if (wv == 0) {
        short8 wf[4];
#pragma unroll
        for (int ks = 0; ks < 4; ++ks) {
            short8 u = {0,0,0,0,0,0,0,0};
            if (r < 3) {
                const float* w = offW2 + r * NC + ks * 32 + q * 8;
                float4 f0 = *(const float4*)w;
                float4 f1 = *(const float4*)(w + 4);
                u[0] = f2bf(f0.x); u[1] = f2bf(f0.y); u[2] = f2bf(f0.z); u[3] = f2bf(f0.w);
                u[4] = f2bf(f1.x); u[5] = f2bf(f1.y); u[6] = f2bf(f1.z); u[7] = f2bf(f1.w);
            }
            wf[ks] = u;
        }
        short8 af[4];
#pragma unroll
        for (int ks = 0; ks < 4; ++ks)
            af[ks] = *(const short8*)&HOFF[hsw(r, ks * 32 + q * 8)];
        floatx4 acc = {0.f, 0.f, 0.f, 0.f};
#pragma unroll
        for (int ks = 0; ks < 4; ++ks)
            acc = MFMA(af[ks], wf[ks], acc);
        if (r < 3 && q < 2) {
#pragma unroll
            for (int i = 0; i < 4; ++i) {
                int p = q * 4 + i;
                s_CTR[p][r] = xyz[(rowbase + p) * 3 + r] + acc[i] + offb2[r];
            }
        }
    }
    __syncthreads();   // B3: centers ready (HOFF dead)

    // zero rel K-ext pads (elems 4..31 per row; multiplied by W1p zero rows,
    // but must be finite bf16)
    if (t < 64) {
        ushort4v z = {0, 0, 0, 0};
#pragma unroll
        for (int gz = 1; gz < 8; ++gz)
            *(ushort4v*)&s_REL[t * RELW + gz * 4] = z;
    }

    // ---------------- edge phase: 2 halves of 64 rows ----------------
    for (int h = 0; h < 2; ++h) {
        // gather 64 rows of bf16 features (VGPR-mediated, swizzled LDS write)
        {
            int rr = t >> 4, c8 = (t & 15) * 8;
#pragma unroll
            for (int pass = 0; pass < 4; ++pass) {
                int row64 = pass * 16 + rr;
                int nb = s_KNN[h * 64 + row64];
                short8 u = *(const short8*)(Fbf + ((size_t)b * NP + nb) * NC + c8);
                *(short8*)&s_EIF[hsw(row64, c8)] = u;
            }
        }
        if (t < 64) {   // rel-pos, direct loads (no local arrays)
            int row64 = t, p = (h << 2) + (t >> 4);
            int nb = s_KNN[h * 64 + row64];
            const float* xp = xyz + ((size_t)b * NP + nb) * 3;
            ushort4v rv = { f2bf(xp[0] - s_CTR[p][0]), f2bf(xp[1] - s_CTR[p][1]),
                            f2bf(xp[2] - s_CTR[p][2]), 0 };
            *(ushort4v*)&s_REL[row64 * RELW] = rv;
        }
        // edge L1 weight frags: loaded PER HALF (scoped — no overlap with the
        // offset stages; L2-hot, all blocks read the same 40 KB)
        short8 wf1[2][5];
#pragma unroll
        for (int c = 0; c < 2; ++c)
#pragma unroll
            for (int ks = 0; ks < 5; ++ks)
                wf1[c][ks] = *(const short8*)(eW1p + ((cg0 + c) * 16 + r) * 160 + ks * 32 + q * 8);
        __syncthreads();   // A: edge inputs ready

        // ---- edge L1
        floatx4 acc1[4][2];
#pragma unroll
        for (int rt = 0; rt < 4; ++rt) {
            short8 af[5];
            int rowb = (rt * 16 + r) << 7;
#pragma unroll
            for (int ks = 0; ks < 4; ++ks)
                af[ks] = *(const short8*)&s_EIF[rowb + ((((ks << 2) + q) ^ r) << 3)];
            af[4] = *(const short8*)&s_REL[(rt * 16 + r) * RELW + q * 8];
            acc1[rt][0] = (floatx4){0.f,0.f,0.f,0.f};
            acc1[rt][1] = (floatx4){0.f,0.f,0.f,0.f};
#pragma unroll
            for (int c = 0; c < 2; ++c)
#pragma unroll
                for (int ks = 0; ks < 5; ++ks)
                    acc1[rt][c] = MFMA(af[ks], wf1[c][ks], acc1[rt][c]);
        }
        __syncthreads();   // B: inputs consumed; H aliases s_EIF

        // ---- bias+relu -> H (swizzled bf16)
#pragma unroll
        for (int rt = 0; rt < 4; ++rt)
#pragma unroll
            for (int c = 0; c < 2; ++c) {
                int col = (cg0 + c) * 16 + r;
#pragma unroll
                for (int i = 0; i < 4; ++i)
                    s_EIF[hsw(rt * 16 + q * 4 + i, col)] =
                        f2bf(fmaxf(acc1[rt][c][i] + eb1v[c], 0.f));
            }
        __syncthreads();   // C: H ready

        // ---- edge L2 + max over K (16-row tile = one point)
        {
            short8 wf2[2][4];
#pragma unroll
            for (int c = 0; c < 2; ++c)
#pragma unroll
                for (int ks = 0; ks < 4; ++ks)
                    wf2[c][ks] = *(const short8*)(eW2p + ((cg0 + c) * 16 + r) * NC + ks * 32 + q * 8);
#pragma unroll
            for (int rt = 0; rt < 4; ++rt) {
                short8 af[4];
                int rowb = (rt * 16 + r) << 7;
#pragma unroll
                for (int ks = 0; ks < 4; ++ks)
                    af[ks] = *(const short8*)&s_EIF[rowb + ((((ks << 2) + q) ^ r) << 3)];
                floatx4 acc[2] = { {0.f,0.f,0.f,0.f}, {0.f,0.f,0.f,0.f} };
#pragma unroll
                for (int c = 0; c < 2; ++c)
#pragma unroll
                    for (int ks = 0; ks < 4; ++ks)
                        acc[c] = MFMA(af[ks], wf2[c][ks], acc[c]);
#pragma unroll
                for (int c = 0; c < 2; ++c) {
                    float m = fmaxf(fmaxf(acc[c][0], acc[c][1]),
                                    fmaxf(acc[c][2], acc[c][3]));
                    m = fmaxf(m, __shfl_xor(m, 16));
                    m = fmaxf(m, __shfl_xor(m, 32));
                    if (q == 0)
                        s_AGG[((h << 2) + rt) * NC + (cg0 + c) * 16 + r] = m + eb2v[c];
                }
            }
        }
        __syncthreads();   // D: H consumed
    }

    // ---------------- UIN assembly [agg | self] (float4 reads)
    {
        int p = t >> 5, c4 = (t & 31) << 2;
        float4 a = *(const float4*)&s_AGG[p * NC + c4];
        float4 f = *(const float4*)&s_FSELF[p * NC + c4];
        ushort4v ua = { f2bf(a.x), f2bf(a.y), f2bf(a.z), f2bf(a.w) };
        ushort4v uf = { f2bf(f.x), f2bf(f.y), f2bf(f.z), f2bf(f.w) };
        *(ushort4v*)&s_EIF[p * UINW + c4] = ua;
        *(ushort4v*)&s_EIF[p * UINW + 128 + c4] = uf;
    }
    __syncthreads();

    // ---------------- update L1 (K=256) -> H2 (s_REL, swizzled)
    {
        short8 wf[2][8];
#pragma unroll
        for (int c = 0; c < 2; ++c)
#pragma unroll
            for (int ks = 0; ks < 8; ++ks)
                wf[c][ks] = *(const short8*)(uW1p + ((cg0 + c) * 16 + r) * 256 + ks * 32 + q * 8);
        short8 af[8];
#pragma unroll
        for (int ks = 0; ks < 8; ++ks)
            af[ks] = *(const short8*)&s_EIF[r * UINW + ks * 32 + q * 8];
        floatx4 acc[2] = { {0.f,0.f,0.f,0.f}, {0.f,0.f,0.f,0.f} };
#pragma unroll
        for (int c = 0; c < 2; ++c)
#pragma unroll
            for (int ks = 0; ks < 8; ++ks)
                acc[c] = MFMA(af[ks], wf[c][ks], acc[c]);
#pragma unroll
        for (int c = 0; c < 2; ++c) {
            int col = (cg0 + c) * 16 + r;
            float bv = ub1[col];
#pragma unroll
            for (int i = 0; i < 4; ++i)
                s_REL[hsw(q * 4 + i, col)] = f2bf(fmaxf(acc[c][i] + bv, 0.f));
        }
    }
    __syncthreads();

    // ---------------- update L2 + residual -> Fout (fp32) + FbfN (bf16)
    {
        short8 wf[2][4];
#pragma unroll
        for (int c = 0; c < 2; ++c)
#pragma unroll
            for (int ks = 0; ks < 4; ++ks)
                wf[c][ks] = *(const short8*)(uW2p + ((cg0 + c) * 16 + r) * NC + ks * 32 + q * 8);
        short8 af[4];
#pragma unroll
        for (int ks = 0; ks < 4; ++ks)
            af[ks] = *(const short8*)&s_REL[hsw(r, ks * 32 + q * 8)];
        floatx4 acc[2] = { {0.f,0.f,0.f,0.f}, {0.f,0.f,0.f,0.f} };
#pragma unroll
        for (int c = 0; c < 2; ++c)
#pragma unroll
            for (int ks = 0; ks < 4; ++ks)
                acc[c] = MFMA(af[ks], wf[c][ks], acc[c]);
        if (q < 2) {
#pragma unroll
            for (int c = 0; c < 2; ++c) {
                int col = (cg0 + c) * 16 + r;
                float bv = ub2[col];
#pragma unroll
                for (int i = 0; i < 4; ++i) {
                    int p = q * 4 + i;   // 0..7
                    float v = s_FSELF[p * NC + col] + acc[c][i] + bv;
                    Fout[(rowbase + p) * NC + col] = v;
                    FbfN[(rowbase + p) * NC + col] = f2bf(v);
                }
            }
        }
    }
}

// ---------------------------------------------------------------------------
extern "C" void kernel_launch(void* const* d_in, const int* in_sizes, int n_in,
                              void* d_out, int out_size, void* d_ws, size_t ws_size,
                              hipStream_t stream)
{
    const float* xyz   = (const float*)d_in[0];
    const float* feat  = (const float*)d_in[1];
    const int*   knn   = (const int*)d_in[2];
    const float* offW1 = (const float*)d_in[3];
    const float* offb1 = (const float*)d_in[4];
    const float* offW2 = (const float*)d_in[5];
    const float* offb2 = (const float*)d_in[6];
    const float* eW1   = (const float*)d_in[7];
    const float* eb1   = (const float*)d_in[8];
    const float* eW2   = (const float*)d_in[9];
    const float* eb2   = (const float*)d_in[10];
    const float* uW1   = (const float*)d_in[11];
    const float* ub1   = (const float*)d_in[12];
    const float* uW2   = (const float*)d_in[13];
    const float* ub2   = (const float*)d_in[14];
    float* out = (float*)d_out;

    char* ws = (char*)d_ws;
    unsigned short* FbfA   = (unsigned short*)ws;                 //  8388608 B
    unsigned short* FbfB   = (unsigned short*)(ws + 8388608);     //  8388608 B
    unsigned short* offW1p = (unsigned short*)(ws + 16777216);    //    32768 B
    unsigned short* eW1p   = (unsigned short*)(ws + 16809984);    //   122880 B
    unsigned short* eW2p   = (unsigned short*)(ws + 16932864);    //    98304 B
    unsigned short* uW1p   = (unsigned short*)(ws + 17031168);    //   196608 B
    unsigned short* uW2p   = (unsigned short*)(ws + 17227776);    //    98304 B

    prep_k<<<3120, 256, 0, stream>>>(feat, offW1, eW1, eW2, uW1, uW2,
                                     FbfA, offW1p, eW1p, eW2p, uW1p, uW2p);

    // fp32 features: feat -> d_out, then in place (own rows only; gathers use
    // the bf16 ping-pong copies emitted by the previous iteration).
    const float*          fin[3] = { feat, out,  out  };
    const unsigned short* fbf[3] = { FbfA, FbfB, FbfA };
    unsigned short*       fbn[3] = { FbfB, FbfA, FbfB };
    for (int tt = 0; tt < 3; ++tt) {
        stab_iter_k<<<4096, 256, 0, stream>>>(
            fin[tt], out, fbf[tt], fbn[tt], xyz, knn,
            offW1p, offW2, offb1, offb2,
            eW1p + tt * 20480, eW2p + tt * 16384, eb1 + tt * 128, eb2 + tt * 128,
            uW1p + tt * 32768, uW2p + tt * 16384, ub1 + tt * 128, ub2 + tt * 128);
    }
}

// Round 6
// 660.740 us; speedup vs baseline: 1.2156x; 1.2156x over previous
//
#include <hip/hip_runtime.h>
#include <cstddef>
#include <cstdint>

#define NB 4
#define NP 8192
#define NK 16
#define NC 128
#define HW_ 136    // center_k LDS row stride (bf16)
#define RELW 40    // rel K-extension row stride (elems): conflict-free
#define UINW 264   // UIN row stride: 132 dw % 32 = 4 -> benign

using short8   = __attribute__((ext_vector_type(8))) short;
using ushort4v = __attribute__((ext_vector_type(4))) unsigned short;
using floatx4  = __attribute__((ext_vector_type(4))) float;

__device__ __forceinline__ unsigned short f2bf(float f) {
    union { float f; unsigned u; } v; v.f = f;
    unsigned r = v.u + 0x7FFFu + ((v.u >> 16) & 1u);   // RNE
    return (unsigned short)(r >> 16);
}

// XOR-swizzled (rows x 128) bf16 tile, phys elem index. 8-col groups stay
// contiguous (b128-friendly); col-group ^= (row&15) spreads banks uniformly.
__device__ __forceinline__ int hsw(int row, int col) {
    return (row << 7) + ((((col >> 3) ^ (row & 15))) << 3) + (col & 7);
}

#define MFMA(a, b, c) __builtin_amdgcn_mfma_f32_16x16x32_bf16((a), (b), (c), 0, 0, 0)

// ---------------------------------------------------------------------------
// Weight packing: fp32 -> bf16, edge_W1 reordered to [feat(128)|rel(3)|pad->160]
// ---------------------------------------------------------------------------
__global__ void pack_weights_k(const float* __restrict__ offW1,
                               const float* __restrict__ eW1,
                               const float* __restrict__ eW2,
                               const float* __restrict__ uW1,
                               const float* __restrict__ uW2,
                               unsigned short* __restrict__ offW1p,
                               unsigned short* __restrict__ eW1p,
                               unsigned short* __restrict__ eW2p,
                               unsigned short* __restrict__ uW1p,
                               unsigned short* __restrict__ uW2p)
{
    int i = blockIdx.x * 256 + threadIdx.x;
    if (i < 16384) { offW1p[i] = f2bf(offW1[i]); return; }
    i -= 16384;
    if (i < 61440) {
        int tt = i / 20480, rem = i % 20480;
        int j = rem / 160, k = rem % 160;
        float v = 0.f;
        if (k < 128)      v = eW1[(tt * 128 + j) * 131 + 3 + k];     // feat part
        else if (k < 131) v = eW1[(tt * 128 + j) * 131 + (k - 128)]; // rel part
        eW1p[i] = f2bf(v);
        return;
    }
    i -= 61440;
    if (i < 49152) { eW2p[i] = f2bf(eW2[i]); return; }
    i -= 49152;
    if (i < 98304) { uW1p[i] = f2bf(uW1[i]); return; }
    i -= 98304;
    if (i < 49152) { uW2p[i] = f2bf(uW2[i]); }
}

// ---------------------------------------------------------------------------
// center_k: offset MLP for 16 points/block. Also emits bf16 feature copy Fbf.
// (Kept as a separate kernel: fusing it into stab_iter_k provably causes
//  scratch spill at the 128-VGPR/wave budget — rounds 3-5.)
// ---------------------------------------------------------------------------
__global__ __launch_bounds__(256, 4)
void center_k(const float* __restrict__ Fin, const float* __restrict__ xyz,
              const unsigned short* __restrict__ offW1p,
              const float* __restrict__ offW2, const float* __restrict__ offb1,
              const float* __restrict__ offb2,
              unsigned short* __restrict__ Fbf, float* __restrict__ ctr)
{
    __shared__ __align__(16) unsigned short sA[16 * HW_];
    __shared__ __align__(16) unsigned short sH[16 * HW_];
    const int t = threadIdx.x, wv = t >> 6, ln = t & 63, q = ln >> 4, r = ln & 15;
    const int base = blockIdx.x * 16;     // global row (b*NP+n) base

    {   // load fp32 -> cvt -> LDS A + global Fbf
        int row = t >> 4, c8 = (t & 15) * 8;
        const float* src = Fin + (size_t)(base + row) * NC + c8;
        float4 f0 = *(const float4*)src;
        float4 f1 = *(const float4*)(src + 4);
        short8 u;
        u[0] = f2bf(f0.x); u[1] = f2bf(f0.y); u[2] = f2bf(f0.z); u[3] = f2bf(f0.w);
        u[4] = f2bf(f1.x); u[5] = f2bf(f1.y); u[6] = f2bf(f1.z); u[7] = f2bf(f1.w);
        *(short8*)&sA[row * HW_ + c8] = u;
        *(short8*)(Fbf + (size_t)(base + row) * NC + c8) = u;
    }
    __syncthreads();

    {   // layer 1
        int cg0 = wv << 1;
        short8 wf[2][4];
#pragma unroll
        for (int c = 0; c < 2; ++c)
#pragma unroll
            for (int ks = 0; ks < 4; ++ks)
                wf[c][ks] = *(const short8*)(offW1p + ((cg0 + c) * 16 + r) * NC + ks * 32 + q * 8);
        short8 af[4];
#pragma unroll
        for (int ks = 0; ks < 4; ++ks)
            af[ks] = *(const short8*)&sA[r * HW_ + ks * 32 + q * 8];
        floatx4 acc[2] = { {0.f,0.f,0.f,0.f}, {0.f,0.f,0.f,0.f} };
#pragma unroll
        for (int c = 0; c < 2; ++c)
#pragma unroll
            for (int ks = 0; ks < 4; ++ks)
                acc[c] = MFMA(af[ks], wf[c][ks], acc[c]);
#pragma unroll
        for (int c = 0; c < 2; ++c) {
            int col = (cg0 + c) * 16 + r;
            float bv = offb1[col];
#pragma unroll
            for (int i = 0; i < 4; ++i)
                sH[(q * 4 + i) * HW_ + col] = f2bf(fmaxf(acc[c][i] + bv, 0.f));
        }
    }
    __syncthreads();

    if (wv == 0) {   // layer 2 (out=3, zero-padded to 16 cols)
        short8 wf[4];
#pragma unroll
        for (int ks = 0; ks < 4; ++ks) {
            short8 u = {0,0,0,0,0,0,0,0};
            if (r < 3) {
                const float* w = offW2 + r * NC + ks * 32 + q * 8;
                float4 f0 = *(const float4*)w;
                float4 f1 = *(const float4*)(w + 4);
                u[0] = f2bf(f0.x); u[1] = f2bf(f0.y); u[2] = f2bf(f0.z); u[3] = f2bf(f0.w);
                u[4] = f2bf(f1.x); u[5] = f2bf(f1.y); u[6] = f2bf(f1.z); u[7] = f2bf(f1.w);
            }
            wf[ks] = u;
        }
        short8 af[4];
#pragma unroll
        for (int ks = 0; ks < 4; ++ks)
            af[ks] = *(const short8*)&sH[r * HW_ + ks * 32 + q * 8];
        floatx4 acc = {0.f, 0.f, 0.f, 0.f};
#pragma unroll
        for (int ks = 0; ks < 4; ++ks)
            acc = MFMA(af[ks], wf[ks], acc);
        if (r < 3) {
#pragma unroll
            for (int i = 0; i < 4; ++i) {
                int p = q * 4 + i;
                ctr[(size_t)(base + p) * 3 + r] =
                    xyz[(size_t)(base + p) * 3 + r] + acc[i] + offb2[r];
            }
        }
    }
}

// ---------------------------------------------------------------------------
// Fused iteration: gather(bf16) -> edge MLP -> max(K) -> update MLP -> residual
// Block = 256 thr (4 waves), 8 points; edge rows in 2 halves of 64.
// LDS ~30.3 KB -> 4 blocks/CU. Swizzled pow-2 LDS tiles (conflict-free).
// ---------------------------------------------------------------------------
__global__ __launch_bounds__(256, 4)
void stab_iter_k(const float* __restrict__ Fin, float* __restrict__ Fout,
                 const unsigned short* __restrict__ Fbf,
                 const float* __restrict__ xyz, const int* __restrict__ knn,
                 const float* __restrict__ ctr,
                 const unsigned short* __restrict__ eW1p,
                 const unsigned short* __restrict__ eW2p,
                 const float* __restrict__ eb1, const float* __restrict__ eb2,
                 const unsigned short* __restrict__ uW1p,
                 const unsigned short* __restrict__ uW2p,
                 const float* __restrict__ ub1, const float* __restrict__ ub2)
{
    __shared__ __align__(16) unsigned short s_EIF[64 * NC];    // 16384 B: feats / H / UIN
    __shared__ __align__(16) unsigned short s_REL[64 * RELW];  //  5120 B: rel / H2
    __shared__ __align__(16) float s_AGG[8 * NC];              //  4096 B
    __shared__ __align__(16) float s_FSELF[8 * NC];            //  4096 B
    __shared__ int   s_KNN[128];                               //   512 B
    __shared__ float s_CTR[8][3];                              //    96 B

    unsigned short* UIN = s_EIF;   // 8 x 264 (alias)
    unsigned short* H2  = s_REL;   // 16 x 128 swizzled (alias; rel dead by then)

    const int xcd  = blockIdx.x & 7;
    const int slot = blockIdx.x >> 3;
    const int b    = xcd >> 1;
    const int n0   = ((slot << 1) | (xcd & 1)) << 3;
    const int t = threadIdx.x, wv = t >> 6, ln = t & 63;
    const int q = ln >> 4, r = ln & 15, cg0 = wv << 1;
    const size_t rowbase = (size_t)b * NP + n0;

    // ---- stage 1: self features (fp32), knn, centers; zero rel pads
    {
        int row = t >> 5, c4 = (t & 31) << 2;
        float4 f = *(const float4*)(Fin + (rowbase + row) * NC + c4);
        *(float4*)&s_FSELF[row * NC + c4] = f;
        if (t < 128)
            s_KNN[t] = knn[(rowbase + (t >> 4)) * NK + (t & 15)];
        if (t < 24) {
            int p = t / 3, o = t % 3;
            s_CTR[p][o] = ctr[(rowbase + p) * 3 + o];
        }
        if (t < 64) {   // zero rel pad elems 4..31 (once; rv writes only 0..3)
            ushort4v z = {0, 0, 0, 0};
#pragma unroll
            for (int gz = 1; gz < 8; ++gz)
                *(ushort4v*)&s_REL[t * RELW + gz * 4] = z;
        }
    }
    // edge L1 weight frags persist across both halves (proven non-spilling
    // in this split-kernel structure — round 2)
    short8 wf1[2][5];
#pragma unroll
    for (int c = 0; c < 2; ++c)
#pragma unroll
        for (int ks = 0; ks < 5; ++ks)
            wf1[c][ks] = *(const short8*)(eW1p + ((cg0 + c) * 16 + r) * 160 + ks * 32 + q * 8);
    float eb1v[2] = { eb1[cg0 * 16 + r], eb1[(cg0 + 1) * 16 + r] };
    float eb2v[2] = { eb2[cg0 * 16 + r], eb2[(cg0 + 1) * 16 + r] };
    __syncthreads();

#pragma unroll
    for (int h = 0; h < 2; ++h) {
        // ---- gather 64 edge rows (bf16, swizzled LDS write) + rel-pos
        {
            int rr = t >> 4, c8 = (t & 15) * 8;
#pragma unroll
            for (int pass = 0; pass < 4; ++pass) {
                int row64 = pass * 16 + rr;
                int nb = s_KNN[h * 64 + row64];
                short8 u = *(const short8*)(Fbf + ((size_t)b * NP + nb) * NC + c8);
                *(short8*)&s_EIF[hsw(row64, c8)] = u;
            }
        }
        if (t < 64) {
            int row64 = t, p = (h << 2) + (t >> 4);
            int nb = s_KNN[h * 64 + row64];
            const float* xp = xyz + ((size_t)b * NP + nb) * 3;
            ushort4v rv = { f2bf(xp[0] - s_CTR[p][0]), f2bf(xp[1] - s_CTR[p][1]),
                            f2bf(xp[2] - s_CTR[p][2]), 0 };
            *(ushort4v*)&s_REL[row64 * RELW] = rv;
        }
        __syncthreads();   // A: edge inputs ready

        // ---- edge L1 (4 row-tiles x 2 col-tiles x 5 K-steps)
        floatx4 acc1[4][2];
#pragma unroll
        for (int rt = 0; rt < 4; ++rt) {
            short8 af[5];
            int rowb = (rt * 16 + r) << 7;
#pragma unroll
            for (int ks = 0; ks < 4; ++ks)
                af[ks] = *(const short8*)&s_EIF[rowb + ((((ks << 2) + q) ^ r) << 3)];
            af[4] = *(const short8*)&s_REL[(rt * 16 + r) * RELW + q * 8];
            acc1[rt][0] = (floatx4){0.f,0.f,0.f,0.f};
            acc1[rt][1] = (floatx4){0.f,0.f,0.f,0.f};
#pragma unroll
            for (int c = 0; c < 2; ++c)
#pragma unroll
                for (int ks = 0; ks < 5; ++ks)
                    acc1[rt][c] = MFMA(af[ks], wf1[c][ks], acc1[rt][c]);
        }
        __syncthreads();   // B: inputs consumed; H aliases s_EIF

        // ---- bias+relu -> H (swizzled bf16)
#pragma unroll
        for (int rt = 0; rt < 4; ++rt)
#pragma unroll
            for (int c = 0; c < 2; ++c) {
                int col = (cg0 + c) * 16 + r;
#pragma unroll
                for (int i = 0; i < 4; ++i)
                    s_EIF[hsw(rt * 16 + q * 4 + i, col)] =
                        f2bf(fmaxf(acc1[rt][c][i] + eb1v[c], 0.f));
            }
        __syncthreads();   // C: H ready

        // ---- edge L2 + max over K (16-row tile = one point)
        {
            short8 wf2[2][4];
#pragma unroll
            for (int c = 0; c < 2; ++c)
#pragma unroll
                for (int ks = 0; ks < 4; ++ks)
                    wf2[c][ks] = *(const short8*)(eW2p + ((cg0 + c) * 16 + r) * NC + ks * 32 + q * 8);
#pragma unroll
            for (int rt = 0; rt < 4; ++rt) {
                short8 af[4];
                int rowb = (rt * 16 + r) << 7;
#pragma unroll
                for (int ks = 0; ks < 4; ++ks)
                    af[ks] = *(const short8*)&s_EIF[rowb + ((((ks << 2) + q) ^ r) << 3)];
                floatx4 acc[2] = { {0.f,0.f,0.f,0.f}, {0.f,0.f,0.f,0.f} };
#pragma unroll
                for (int c = 0; c < 2; ++c)
#pragma unroll
                    for (int ks = 0; ks < 4; ++ks)
                        acc[c] = MFMA(af[ks], wf2[c][ks], acc[c]);
#pragma unroll
                for (int c = 0; c < 2; ++c) {
                    float m = fmaxf(fmaxf(acc[c][0], acc[c][1]),
                                    fmaxf(acc[c][2], acc[c][3]));
                    m = fmaxf(m, __shfl_xor(m, 16));
                    m = fmaxf(m, __shfl_xor(m, 32));
                    if (q == 0)
                        s_AGG[((h << 2) + rt) * NC + (cg0 + c) * 16 + r] = m + eb2v[c];
                }
            }
        }
        __syncthreads();   // D: H consumed
    }

    // ---- UIN assembly [agg(128)|self(128)] (float4 LDS reads: bank-uniform)
    {
        int p = t >> 5, c4 = (t & 31) << 2;
        float4 a = *(const float4*)&s_AGG[p * NC + c4];
        float4 f = *(const float4*)&s_FSELF[p * NC + c4];
        ushort4v ua = { f2bf(a.x), f2bf(a.y), f2bf(a.z), f2bf(a.w) };
        ushort4v uf = { f2bf(f.x), f2bf(f.y), f2bf(f.z), f2bf(f.w) };
        *(ushort4v*)&UIN[p * UINW + c4] = ua;
        *(ushort4v*)&UIN[p * UINW + 128 + c4] = uf;
    }
    __syncthreads();

    // ---- update L1 (K=256) -> H2 (swizzled)
    {
        short8 wf[2][8];
#pragma unroll
        for (int c = 0; c < 2; ++c)
#pragma unroll
            for (int ks = 0; ks < 8; ++ks)
                wf[c][ks] = *(const short8*)(uW1p + ((cg0 + c) * 16 + r) * 256 + ks * 32 + q * 8);
        short8 af[8];
#pragma unroll
        for (int ks = 0; ks < 8; ++ks)
            af[ks] = *(const short8*)&UIN[r * UINW + ks * 32 + q * 8];
        floatx4 acc[2] = { {0.f,0.f,0.f,0.f}, {0.f,0.f,0.f,0.f} };
#pragma unroll
        for (int c = 0; c < 2; ++c)
#pragma unroll
            for (int ks = 0; ks < 8; ++ks)
                acc[c] = MFMA(af[ks], wf[c][ks], acc[c]);
#pragma unroll
        for (int c = 0; c < 2; ++c) {
            int col = (cg0 + c) * 16 + r;
            float bv = ub1[col];
#pragma unroll
            for (int i = 0; i < 4; ++i)
                H2[hsw(q * 4 + i, col)] = f2bf(fmaxf(acc[c][i] + bv, 0.f));
        }
    }
    __syncthreads();

    // ---- update L2 + residual -> Fout
    {
        short8 wf[2][4];
#pragma unroll
        for (int c = 0; c < 2; ++c)
#pragma unroll
            for (int ks = 0; ks < 4; ++ks)
                wf[c][ks] = *(const short8*)(uW2p + ((cg0 + c) * 16 + r) * NC + ks * 32 + q * 8);
        short8 af[4];
#pragma unroll
        for (int ks = 0; ks < 4; ++ks)
            af[ks] = *(const short8*)&H2[hsw(r, ks * 32 + q * 8)];
        floatx4 acc[2] = { {0.f,0.f,0.f,0.f}, {0.f,0.f,0.f,0.f} };
#pragma unroll
        for (int c = 0; c < 2; ++c)
#pragma unroll
            for (int ks = 0; ks < 4; ++ks)
                acc[c] = MFMA(af[ks], wf[c][ks], acc[c]);
        if (q < 2) {
#pragma unroll
            for (int c = 0; c < 2; ++c) {
                int col = (cg0 + c) * 16 + r;
                float bv = ub2[col];
#pragma unroll
                for (int i = 0; i < 4; ++i) {
                    int p = q * 4 + i;   // 0..7
                    Fout[(rowbase + p) * NC + col] =
                        s_FSELF[p * NC + col] + acc[c][i] + bv;
                }
            }
        }
    }
}

// ---------------------------------------------------------------------------
extern "C" void kernel_launch(void* const* d_in, const int* in_sizes, int n_in,
                              void* d_out, int out_size, void* d_ws, size_t ws_size,
                              hipStream_t stream)
{
    const float* xyz   = (const float*)d_in[0];
    const float* feat  = (const float*)d_in[1];
    const int*   knn   = (const int*)d_in[2];
    const float* offW1 = (const float*)d_in[3];
    const float* offb1 = (const float*)d_in[4];
    const float* offW2 = (const float*)d_in[5];
    const float* offb2 = (const float*)d_in[6];
    const float* eW1   = (const float*)d_in[7];
    const float* eb1   = (const float*)d_in[8];
    const float* eW2   = (const float*)d_in[9];
    const float* eb2   = (const float*)d_in[10];
    const float* uW1   = (const float*)d_in[11];
    const float* ub1   = (const float*)d_in[12];
    const float* uW2   = (const float*)d_in[13];
    const float* ub2   = (const float*)d_in[14];
    float* out = (float*)d_out;

    char* ws = (char*)d_ws;
    unsigned short* Fbf    = (unsigned short*)ws;                 // 8388608 B
    float*          ctrb   = (float*)(ws + 8388608);              // 393216 B
    unsigned short* offW1p = (unsigned short*)(ws + 8781824);     // 32768 B
    unsigned short* eW1p   = (unsigned short*)(ws + 8814592);     // 122880 B
    unsigned short* eW2p   = (unsigned short*)(ws + 8937472);     // 98304 B
    unsigned short* uW1p   = (unsigned short*)(ws + 9035776);     // 196608 B
    unsigned short* uW2p   = (unsigned short*)(ws + 9232384);     // 98304 B

    pack_weights_k<<<1072, 256, 0, stream>>>(offW1, eW1, eW2, uW1, uW2,
                                             offW1p, eW1p, eW2p, uW1p, uW2p);

    // fp32 features: feat -> d_out (t=0), then in place in d_out (only the
    // owning block reads/writes its rows; gathers use the bf16 copy Fbf,
    // which center_k regenerates before each fused launch).
    const float* fin[3] = { feat, out, out };
    for (int tt = 0; tt < 3; ++tt) {
        center_k<<<2048, 256, 0, stream>>>(fin[tt], xyz, offW1p, offW2,
                                           offb1, offb2, Fbf, ctrb);
        stab_iter_k<<<4096, 256, 0, stream>>>(
            fin[tt], out, Fbf, xyz, knn, ctrb,
            eW1p + tt * 20480, eW2p + tt * 16384, eb1 + tt * 128, eb2 + tt * 128,
            uW1p + tt * 32768, uW2p + tt * 16384, ub1 + tt * 128, ub2 + tt * 128);
    }
}

// Round 7
// 561.935 us; speedup vs baseline: 1.4293x; 1.1758x over previous
//
#include <hip/hip_runtime.h>
#include <cstddef>
#include <cstdint>

#define NB 4
#define NP 8192
#define NK 16
#define NC 128
#define EIW 168   // EI row stride (bf16), linear — NO swizzle (r6 lesson: swizzle
                  // address math raises reg pressure -> scratch spill)
#define HW_ 136   // H / H2 row stride
#define UINW 264  // UIN row stride

using short8   = __attribute__((ext_vector_type(8))) short;
using ushort4v = __attribute__((ext_vector_type(4))) unsigned short;
using floatx4  = __attribute__((ext_vector_type(4))) float;

__device__ __forceinline__ unsigned short f2bf(float f) {
    union { float f; unsigned u; } v; v.f = f;
    unsigned r = v.u + 0x7FFFu + ((v.u >> 16) & 1u);   // RNE
    return (unsigned short)(r >> 16);
}

#define MFMA(a, b, c) __builtin_amdgcn_mfma_f32_16x16x32_bf16((a), (b), (c), 0, 0, 0)

// ---------------------------------------------------------------------------
// Weight packing: fp32 -> bf16, edge_W1 reordered to [feat(128)|rel(3)|pad->160]
// ---------------------------------------------------------------------------
__global__ void pack_weights_k(const float* __restrict__ offW1,
                               const float* __restrict__ eW1,
                               const float* __restrict__ eW2,
                               const float* __restrict__ uW1,
                               const float* __restrict__ uW2,
                               unsigned short* __restrict__ offW1p,
                               unsigned short* __restrict__ eW1p,
                               unsigned short* __restrict__ eW2p,
                               unsigned short* __restrict__ uW1p,
                               unsigned short* __restrict__ uW2p)
{
    int i = blockIdx.x * 256 + threadIdx.x;
    if (i < 16384) { offW1p[i] = f2bf(offW1[i]); return; }
    i -= 16384;
    if (i < 61440) {
        int tt = i / 20480, rem = i % 20480;
        int j = rem / 160, k = rem % 160;
        float v = 0.f;
        if (k < 128)      v = eW1[(tt * 128 + j) * 131 + 3 + k];     // feat part
        else if (k < 131) v = eW1[(tt * 128 + j) * 131 + (k - 128)]; // rel part
        eW1p[i] = f2bf(v);
        return;
    }
    i -= 61440;
    if (i < 49152) { eW2p[i] = f2bf(eW2[i]); return; }
    i -= 49152;
    if (i < 98304) { uW1p[i] = f2bf(uW1[i]); return; }
    i -= 98304;
    if (i < 49152) { uW2p[i] = f2bf(uW2[i]); }
}

// ---------------------------------------------------------------------------
// center_k: offset MLP for 16 points/block + bf16 feature copy Fbf.
// ---------------------------------------------------------------------------
__global__ __launch_bounds__(256, 4)
void center_k(const float* __restrict__ Fin, const float* __restrict__ xyz,
              const unsigned short* __restrict__ offW1p,
              const float* __restrict__ offW2, const float* __restrict__ offb1,
              const float* __restrict__ offb2,
              unsigned short* __restrict__ Fbf, float* __restrict__ ctr)
{
    __shared__ __align__(16) unsigned short sA[16 * HW_];
    __shared__ __align__(16) unsigned short sH[16 * HW_];
    const int t = threadIdx.x, wv = t >> 6, ln = t & 63, q = ln >> 4, r = ln & 15;
    const int base = blockIdx.x * 16;     // global row (b*NP+n) base

    {   // load fp32 -> cvt -> LDS A + global Fbf
        int row = t >> 4, c8 = (t & 15) * 8;
        const float* src = Fin + (size_t)(base + row) * NC + c8;
        float4 f0 = *(const float4*)src;
        float4 f1 = *(const float4*)(src + 4);
        short8 u;
        u[0] = f2bf(f0.x); u[1] = f2bf(f0.y); u[2] = f2bf(f0.z); u[3] = f2bf(f0.w);
        u[4] = f2bf(f1.x); u[5] = f2bf(f1.y); u[6] = f2bf(f1.z); u[7] = f2bf(f1.w);
        *(short8*)&sA[row * HW_ + c8] = u;
        *(short8*)(Fbf + (size_t)(base + row) * NC + c8) = u;
    }
    __syncthreads();

    {   // layer 1
        int cg0 = wv << 1;
        short8 wf[2][4];
#pragma unroll
        for (int c = 0; c < 2; ++c)
#pragma unroll
            for (int ks = 0; ks < 4; ++ks)
                wf[c][ks] = *(const short8*)(offW1p + ((cg0 + c) * 16 + r) * NC + ks * 32 + q * 8);
        short8 af[4];
#pragma unroll
        for (int ks = 0; ks < 4; ++ks)
            af[ks] = *(const short8*)&sA[r * HW_ + ks * 32 + q * 8];
        floatx4 acc[2] = { {0.f,0.f,0.f,0.f}, {0.f,0.f,0.f,0.f} };
#pragma unroll
        for (int c = 0; c < 2; ++c)
#pragma unroll
            for (int ks = 0; ks < 4; ++ks)
                acc[c] = MFMA(af[ks], wf[c][ks], acc[c]);
#pragma unroll
        for (int c = 0; c < 2; ++c) {
            int col = (cg0 + c) * 16 + r;
            float bv = offb1[col];
#pragma unroll
            for (int i = 0; i < 4; ++i)
                sH[(q * 4 + i) * HW_ + col] = f2bf(fmaxf(acc[c][i] + bv, 0.f));
        }
    }
    __syncthreads();

    if (wv == 0) {   // layer 2 (out=3, zero-padded to 16 cols)
        short8 wf[4];
#pragma unroll
        for (int ks = 0; ks < 4; ++ks) {
            short8 u = {0,0,0,0,0,0,0,0};
            if (r < 3) {
                const float* w = offW2 + r * NC + ks * 32 + q * 8;
                float4 f0 = *(const float4*)w;
                float4 f1 = *(const float4*)(w + 4);
                u[0] = f2bf(f0.x); u[1] = f2bf(f0.y); u[2] = f2bf(f0.z); u[3] = f2bf(f0.w);
                u[4] = f2bf(f1.x); u[5] = f2bf(f1.y); u[6] = f2bf(f1.z); u[7] = f2bf(f1.w);
            }
            wf[ks] = u;
        }
        short8 af[4];
#pragma unroll
        for (int ks = 0; ks < 4; ++ks)
            af[ks] = *(const short8*)&sH[r * HW_ + ks * 32 + q * 8];
        floatx4 acc = {0.f, 0.f, 0.f, 0.f};
#pragma unroll
        for (int ks = 0; ks < 4; ++ks)
            acc = MFMA(af[ks], wf[ks], acc);
        if (r < 3) {
#pragma unroll
            for (int i = 0; i < 4; ++i) {
                int p = q * 4 + i;
                ctr[(size_t)(base + p) * 3 + r] =
                    xyz[(size_t)(base + p) * 3 + r] + acc[i] + offb2[r];
            }
        }
    }
}

// ---------------------------------------------------------------------------
// Fused iteration: gather(bf16) -> edge MLP -> max(K) -> update MLP -> residual
// Block = 256 thr (4 waves), 16 points; edge rows in 4 halves of 64.
// LDS ~39.1 KB -> 4 blocks/CU (156 KB). Linear LDS layouts (r2-proven,
// no swizzle). 16-pt block halves per-point L2 weight traffic vs r2.
// ---------------------------------------------------------------------------
__global__ __launch_bounds__(256, 4)
void stab_iter_k(const float* __restrict__ Fin, float* __restrict__ Fout,
                 const unsigned short* __restrict__ Fbf,
                 const float* __restrict__ xyz, const int* __restrict__ knn,
                 const float* __restrict__ ctr,
                 const unsigned short* __restrict__ eW1p,
                 const unsigned short* __restrict__ eW2p,
                 const float* __restrict__ eb1, const float* __restrict__ eb2,
                 const unsigned short* __restrict__ uW1p,
                 const unsigned short* __restrict__ uW2p,
                 const float* __restrict__ ub1, const float* __restrict__ ub2)
{
    __shared__ __align__(16) unsigned short s_EI[64 * EIW];   // 21504 B
    __shared__ __align__(16) float s_AGG[16 * NC];            //  8192 B
    __shared__ __align__(16) float s_FSELF[16 * NC];          //  8192 B
    __shared__ int   s_KNN[256];                              //  1024 B
    __shared__ float s_CTR[16][3];                            //   192 B

    unsigned short* UIN = s_EI;                                    // 16 x 264 (alias)
    unsigned short* H2  = (unsigned short*)((char*)s_EI + 16384);  // 16 x 136 (alias)

    // XCD swizzle: batch b -> XCDs {2b, 2b+1} (L2 locality for gathers)
    const int xcd  = blockIdx.x & 7;
    const int slot = blockIdx.x >> 3;
    const int b    = xcd >> 1;
    const int n0   = ((slot << 1) | (xcd & 1)) << 4;   // 16 points per block
    const int t = threadIdx.x, wv = t >> 6, ln = t & 63;
    const int q = ln >> 4, r = ln & 15, cg0 = wv << 1;
    const size_t rowbase = (size_t)b * NP + n0;

    // ---- stage 1: self features (fp32), knn, centers
    {
        int row = t >> 4, c8 = (t & 15) * 8;
        const float* src = Fin + (rowbase + row) * NC + c8;
        float4 f0 = *(const float4*)src;
        float4 f1 = *(const float4*)(src + 4);
        *(float4*)&s_FSELF[row * NC + c8]     = f0;
        *(float4*)&s_FSELF[row * NC + c8 + 4] = f1;
        s_KNN[t] = knn[(rowbase + (t >> 4)) * NK + (t & 15)];
        if (t < 48) {
            int p = t / 3, o = t % 3;
            s_CTR[p][o] = ctr[(rowbase + p) * 3 + o];
        }
    }
    // edge L1 weight frags persist across all 4 halves (r2-proven non-spilling)
    short8 wf1[2][5];
#pragma unroll
    for (int c = 0; c < 2; ++c)
#pragma unroll
        for (int ks = 0; ks < 5; ++ks)
            wf1[c][ks] = *(const short8*)(eW1p + ((cg0 + c) * 16 + r) * 160 + ks * 32 + q * 8);
    float eb1v[2] = { eb1[cg0 * 16 + r], eb1[(cg0 + 1) * 16 + r] };
    float eb2v[2] = { eb2[cg0 * 16 + r], eb2[(cg0 + 1) * 16 + r] };
    __syncthreads();

#pragma unroll 1
    for (int h = 0; h < 4; ++h) {
        // ---- gather 64 edge rows (bf16) + rel-pos
        {
            int rr = t >> 4, c8 = (t & 15) * 8;
#pragma unroll
            for (int pass = 0; pass < 4; ++pass) {
                int row64 = pass * 16 + rr;
                int nb = s_KNN[h * 64 + row64];
                short8 u = *(const short8*)(Fbf + ((size_t)b * NP + nb) * NC + c8);
                *(short8*)&s_EI[row64 * EIW + c8] = u;
            }
        }
        if (t < 64) {
            int row64 = t, p = (h << 2) + (t >> 4);
            int nb = s_KNN[h * 64 + row64];
            const float* xp = xyz + ((size_t)b * NP + nb) * 3;
            ushort4v rv = { f2bf(xp[0] - s_CTR[p][0]), f2bf(xp[1] - s_CTR[p][1]),
                            f2bf(xp[2] - s_CTR[p][2]), 0 };
            *(ushort4v*)&s_EI[row64 * EIW + 128] = rv;
            ushort4v z = {0, 0, 0, 0};
#pragma unroll
            for (int g = 1; g < 8; ++g)
                *(ushort4v*)&s_EI[row64 * EIW + 128 + g * 4] = z;
        }
        __syncthreads();   // A: edge inputs ready

        // ---- edge L1 (4 row-tiles x 2 col-tiles x 5 K-steps)
        floatx4 acc1[4][2];
#pragma unroll
        for (int rt = 0; rt < 4; ++rt) {
            short8 af[5];
#pragma unroll
            for (int ks = 0; ks < 5; ++ks)
                af[ks] = *(const short8*)&s_EI[(rt * 16 + r) * EIW + ks * 32 + q * 8];
            acc1[rt][0] = (floatx4){0.f,0.f,0.f,0.f};
            acc1[rt][1] = (floatx4){0.f,0.f,0.f,0.f};
#pragma unroll
            for (int c = 0; c < 2; ++c)
#pragma unroll
                for (int ks = 0; ks < 5; ++ks)
                    acc1[rt][c] = MFMA(af[ks], wf1[c][ks], acc1[rt][c]);
        }
        __syncthreads();   // B: inputs consumed; H aliases s_EI

        // ---- bias+relu -> H (bf16, stride 136)
#pragma unroll
        for (int rt = 0; rt < 4; ++rt)
#pragma unroll
            for (int c = 0; c < 2; ++c) {
                int col = (cg0 + c) * 16 + r;
#pragma unroll
                for (int i = 0; i < 4; ++i)
                    s_EI[(rt * 16 + q * 4 + i) * HW_ + col] =
                        f2bf(fmaxf(acc1[rt][c][i] + eb1v[c], 0.f));
            }
        __syncthreads();   // C: H ready

        // ---- edge L2 + max over K (16-row tile = one point)
        {
            short8 wf2[2][4];
#pragma unroll
            for (int c = 0; c < 2; ++c)
#pragma unroll
                for (int ks = 0; ks < 4; ++ks)
                    wf2[c][ks] = *(const short8*)(eW2p + ((cg0 + c) * 16 + r) * NC + ks * 32 + q * 8);
#pragma unroll
            for (int rt = 0; rt < 4; ++rt) {
                short8 af[4];
#pragma unroll
                for (int ks = 0; ks < 4; ++ks)
                    af[ks] = *(const short8*)&s_EI[(rt * 16 + r) * HW_ + ks * 32 + q * 8];
                floatx4 acc[2] = { {0.f,0.f,0.f,0.f}, {0.f,0.f,0.f,0.f} };
#pragma unroll
                for (int c = 0; c < 2; ++c)
#pragma unroll
                    for (int ks = 0; ks < 4; ++ks)
                        acc[c] = MFMA(af[ks], wf2[c][ks], acc[c]);
#pragma unroll
                for (int c = 0; c < 2; ++c) {
                    float m = fmaxf(fmaxf(acc[c][0], acc[c][1]),
                                    fmaxf(acc[c][2], acc[c][3]));
                    m = fmaxf(m, __shfl_xor(m, 16));
                    m = fmaxf(m, __shfl_xor(m, 32));
                    if (q == 0)
                        s_AGG[((h << 2) + rt) * NC + (cg0 + c) * 16 + r] = m + eb2v[c];
                }
            }
        }
        __syncthreads();   // D: H consumed
    }

    // ---- UIN assembly [agg(128)|self(128)] bf16, rows 0..15 (float4 reads)
    {
        int p = t >> 4, c8 = (t & 15) * 8;
        float4 a0 = *(const float4*)&s_AGG[p * NC + c8];
        float4 a1 = *(const float4*)&s_AGG[p * NC + c8 + 4];
        float4 f0 = *(const float4*)&s_FSELF[p * NC + c8];
        float4 f1 = *(const float4*)&s_FSELF[p * NC + c8 + 4];
        short8 ua, uf;
        ua[0] = f2bf(a0.x); ua[1] = f2bf(a0.y); ua[2] = f2bf(a0.z); ua[3] = f2bf(a0.w);
        ua[4] = f2bf(a1.x); ua[5] = f2bf(a1.y); ua[6] = f2bf(a1.z); ua[7] = f2bf(a1.w);
        uf[0] = f2bf(f0.x); uf[1] = f2bf(f0.y); uf[2] = f2bf(f0.z); uf[3] = f2bf(f0.w);
        uf[4] = f2bf(f1.x); uf[5] = f2bf(f1.y); uf[6] = f2bf(f1.z); uf[7] = f2bf(f1.w);
        *(short8*)&UIN[p * UINW + c8]       = ua;
        *(short8*)&UIN[p * UINW + 128 + c8] = uf;
    }
    __syncthreads();

    // ---- update L1 (K=256) -> H2 (stride 136)
    {
        short8 wf[2][8];
#pragma unroll
        for (int c = 0; c < 2; ++c)
#pragma unroll
            for (int ks = 0; ks < 8; ++ks)
                wf[c][ks] = *(const short8*)(uW1p + ((cg0 + c) * 16 + r) * 256 + ks * 32 + q * 8);
        short8 af[8];
#pragma unroll
        for (int ks = 0; ks < 8; ++ks)
            af[ks] = *(const short8*)&UIN[r * UINW + ks * 32 + q * 8];
        floatx4 acc[2] = { {0.f,0.f,0.f,0.f}, {0.f,0.f,0.f,0.f} };
#pragma unroll
        for (int c = 0; c < 2; ++c)
#pragma unroll
            for (int ks = 0; ks < 8; ++ks)
                acc[c] = MFMA(af[ks], wf[c][ks], acc[c]);
#pragma unroll
        for (int c = 0; c < 2; ++c) {
            int col = (cg0 + c) * 16 + r;
            float bv = ub1[col];
#pragma unroll
            for (int i = 0; i < 4; ++i)
                H2[(q * 4 + i) * HW_ + col] = f2bf(fmaxf(acc[c][i] + bv, 0.f));
        }
    }
    __syncthreads();

    // ---- update L2 + residual -> Fout (all 16 rows real now)
    {
        short8 wf[2][4];
#pragma unroll
        for (int c = 0; c < 2; ++c)
#pragma unroll
            for (int ks = 0; ks < 4; ++ks)
                wf[c][ks] = *(const short8*)(uW2p + ((cg0 + c) * 16 + r) * NC + ks * 32 + q * 8);
        short8 af[4];
#pragma unroll
        for (int ks = 0; ks < 4; ++ks)
            af[ks] = *(const short8*)&H2[r * HW_ + ks * 32 + q * 8];
        floatx4 acc[2] = { {0.f,0.f,0.f,0.f}, {0.f,0.f,0.f,0.f} };
#pragma unroll
        for (int c = 0; c < 2; ++c)
#pragma unroll
            for (int ks = 0; ks < 4; ++ks)
                acc[c] = MFMA(af[ks], wf[c][ks], acc[c]);
#pragma unroll
        for (int c = 0; c < 2; ++c) {
            int col = (cg0 + c) * 16 + r;
            float bv = ub2[col];
#pragma unroll
            for (int i = 0; i < 4; ++i) {
                int p = q * 4 + i;   // 0..15
                Fout[(rowbase + p) * NC + col] =
                    s_FSELF[p * NC + col] + acc[c][i] + bv;
            }
        }
    }
}

// ---------------------------------------------------------------------------
extern "C" void kernel_launch(void* const* d_in, const int* in_sizes, int n_in,
                              void* d_out, int out_size, void* d_ws, size_t ws_size,
                              hipStream_t stream)
{
    const float* xyz   = (const float*)d_in[0];
    const float* feat  = (const float*)d_in[1];
    const int*   knn   = (const int*)d_in[2];
    const float* offW1 = (const float*)d_in[3];
    const float* offb1 = (const float*)d_in[4];
    const float* offW2 = (const float*)d_in[5];
    const float* offb2 = (const float*)d_in[6];
    const float* eW1   = (const float*)d_in[7];
    const float* eb1   = (const float*)d_in[8];
    const float* eW2   = (const float*)d_in[9];
    const float* eb2   = (const float*)d_in[10];
    const float* uW1   = (const float*)d_in[11];
    const float* ub1   = (const float*)d_in[12];
    const float* uW2   = (const float*)d_in[13];
    const float* ub2   = (const float*)d_in[14];
    float* out = (float*)d_out;

    char* ws = (char*)d_ws;
    unsigned short* Fbf    = (unsigned short*)ws;                 // 8388608 B
    float*          ctrb   = (float*)(ws + 8388608);              // 393216 B
    unsigned short* offW1p = (unsigned short*)(ws + 8781824);     // 32768 B
    unsigned short* eW1p   = (unsigned short*)(ws + 8814592);     // 122880 B
    unsigned short* eW2p   = (unsigned short*)(ws + 8937472);     // 98304 B
    unsigned short* uW1p   = (unsigned short*)(ws + 9035776);     // 196608 B
    unsigned short* uW2p   = (unsigned short*)(ws + 9232384);     // 98304 B

    pack_weights_k<<<1072, 256, 0, stream>>>(offW1, eW1, eW2, uW1, uW2,
                                             offW1p, eW1p, eW2p, uW1p, uW2p);

    // fp32 features: feat -> d_out (t=0), then in place in d_out (only the
    // owning block reads/writes its rows; gathers use the bf16 copy Fbf,
    // which center_k regenerates before each fused launch).
    const float* fin[3] = { feat, out, out };
    for (int tt = 0; tt < 3; ++tt) {
        center_k<<<2048, 256, 0, stream>>>(fin[tt], xyz, offW1p, offW2,
                                           offb1, offb2, Fbf, ctrb);
        stab_iter_k<<<2048, 256, 0, stream>>>(
            fin[tt], out, Fbf, xyz, knn, ctrb,
            eW1p + tt * 20480, eW2p + tt * 16384, eb1 + tt * 128, eb2 + tt * 128,
            uW1p + tt * 32768, uW2p + tt * 16384, ub1 + tt * 128, ub2 + tt * 128);
    }
}